// Round 2
// baseline (335.694 us; speedup 1.0000x reference)
//
#include <hip/hip_runtime.h>
#include <hip/hip_bf16.h>

// B=1, H=16, S=2048, KV=4096, D=64
// out[q][d] = (KEEP/sum_k p_k) * sum_k (drop_k * p_k * V[k][d]), p=exp(s-m),
// s = qk/8 + structured 0/1 additive mask; denominator has NO dropout.

#define H_   16
#define S_   2048
#define KV_  4096
#define D_   64
#define NCH  64                 // KV_/64 chunks
#define LOG2E 1.4426950408889634f

using bf16x8 = __attribute__((ext_vector_type(8))) __bf16;
using bf16x4 = __attribute__((ext_vector_type(4))) __bf16;
using f32x4  = __attribute__((ext_vector_type(4))) float;

constexpr float KEEP_SCALE = (float)(1.0 / (1.0 - 0.31881923790897965));

// ---- workspace layout (ws is ~2GB; we use ~33MB) ----
#define WS_FLAG   0
#define WS_MBITS  256                      // 32768 rows * 64 u64 = 16 MB
#define WS_K      (256 + 16777216)         // 8 MB bf16 swizzled K tiles
#define WS_V      (WS_K + 8388608)         // 8 MB bf16 swizzled V^T tiles

// ---------------------------------------------------------------------------
// Detect mask storage: 4-byte elems (int/float 0|1) vs 1-byte bool.
// ---------------------------------------------------------------------------
__global__ void detect_mask(const unsigned* __restrict__ m, int* __restrict__ flag) {
    __shared__ int bad;
    if (threadIdx.x == 0) bad = 0;
    __syncthreads();
    int ok = 1;
    for (int i = threadIdx.x; i < 4096; i += blockDim.x) {
        unsigned w = m[i];
        if (w > 1u && w != 0x3F800000u) ok = 0;
    }
    if (!ok) atomicOr(&bad, 1);
    __syncthreads();
    if (threadIdx.x == 0) *flag = bad;
}

// ---------------------------------------------------------------------------
// Bit-pack drop_mask: one u64 word per 64 kv, via wave ballot.
// word W covers elements [W*64, W*64+64); bit i = element W*64+i nonzero.
// ---------------------------------------------------------------------------
__global__ __launch_bounds__(256)
void pack_mask(const unsigned char* __restrict__ mb, const unsigned* __restrict__ mw,
               const int* __restrict__ flag, unsigned long long* __restrict__ bits) {
    const int lane = threadIdx.x & 63;
    const int wid  = (blockIdx.x * blockDim.x + threadIdx.x) >> 6;
    const int nw   = (gridDim.x * blockDim.x) >> 6;
    const bool byteMode = (*flag != 0);
    const int NW = (H_ * S_) * (KV_ / 64);
    for (int W = wid; W < NW; W += nw) {
        const size_t base = (size_t)W * 64 + lane;
        bool keep = byteMode ? (mb[base] != 0) : (mw[base] != 0);
        unsigned long long b = __ballot(keep);
        if (lane == 0) bits[W] = b;
    }
}

// ---------------------------------------------------------------------------
// Pre-convert K -> bf16 tiles [h][chunk][8192B], PRE-SWIZZLED so that a linear
// global_load_lds copy yields LDS image: byte o holds K[row=o>>7][col where
// colbyte = (o&127) ^ ((row&7)<<4)]. Reads then XOR the same swizzle.
// ---------------------------------------------------------------------------
__global__ __launch_bounds__(256)
void conv_k(const float* __restrict__ K, char* __restrict__ out) {
    const unsigned u = blockIdx.x * 256 + threadIdx.x;   // 16B chunk id (524288 total)
    const unsigned tile = u >> 9;                        // h*64 + c
    const unsigned w = u & 511;
    const unsigned row = w >> 3;                         // kv within chunk
    const unsigned colb = ((w & 7) * 16) ^ ((row & 7) << 4);
    const unsigned dcol = colb >> 1;
    const unsigned h = tile >> 6, c = tile & 63;
    const float* src = K + (((size_t)h * KV_) + c * 64 + row) * D_ + dcol;
    f32x4 f0 = *(const f32x4*)src;
    f32x4 f1 = *(const f32x4*)(src + 4);
    bf16x8 b;
    #pragma unroll
    for (int e = 0; e < 4; ++e) { b[e] = (__bf16)f0[e]; b[4 + e] = (__bf16)f1[e]; }
    *(bf16x8*)(out + (size_t)u * 16) = b;
}

// V^T tiles: row = d (0..63), cols = 64 kv of the chunk, same swizzle.
__global__ __launch_bounds__(256)
void conv_v(const float* __restrict__ V, char* __restrict__ out) {
    const unsigned u = blockIdx.x * 256 + threadIdx.x;
    const unsigned tile = u >> 9;
    const unsigned w = u & 511;
    const unsigned d = w >> 3;
    const unsigned colb = ((w & 7) * 16) ^ ((d & 7) << 4);
    const unsigned kv0 = colb >> 1;
    const unsigned h = tile >> 6, c = tile & 63;
    const float* src = V + (((size_t)h * KV_) + c * 64 + kv0) * D_ + d;
    bf16x8 b;
    #pragma unroll
    for (int j = 0; j < 8; ++j) b[j] = (__bf16)src[j * D_];
    *(bf16x8*)(out + (size_t)u * 16) = b;
}

// ---------------------------------------------------------------------------
// Main flash attention. 4 waves/block, 16 q rows/wave, chunk = 64 kv.
// Swapped QK^T (S^T = mfma(K,Q)); K/V^T staged bf16 via global_load_lds
// (pre-swizzled source -> swizzled LDS); 2-phase double buffer.
// ---------------------------------------------------------------------------
__device__ __forceinline__ void gld16(const void* g, void* l) {
    __builtin_amdgcn_global_load_lds(
        (const __attribute__((address_space(1))) unsigned*)g,
        (__attribute__((address_space(3))) unsigned*)l, 16, 0, 0);
}

__global__ __launch_bounds__(256, 2)
void attn_fwd(const float* __restrict__ Q,
              const unsigned long long* __restrict__ Mbits,
              const char* __restrict__ Ktiles,
              const char* __restrict__ Vtiles,
              float* __restrict__ Out)
{
    // [2 bufs x (K 8KB | V 8KB)] + [4 waves x 2KB P tile]
    __shared__ char smem[2 * 16384 + 4 * 2048];

    const int tid  = threadIdx.x;
    const int wave = tid >> 6;
    const int lane = tid & 63;
    const int lq   = lane & 15;
    const int g    = lane >> 4;
    const int swz  = (lq & 7) << 4;

    // XCD-aware bijective swizzle (512 % 8 == 0)
    const int bid = blockIdx.x;
    const int wg  = (bid & 7) * 64 + (bid >> 3);
    const int h   = wg >> 5;
    const int qb  = wg & 31;
    const int q0  = qb * 64 + wave * 16;
    const int q_g = q0 + lq;

    // Q fragments (B operand): lane holds Q[q_g][g*8 + 32*kk + e]
    bf16x8 bq[2];
    {
        const float* qrow = Q + ((size_t)h * S_ + q_g) * D_ + g * 8;
        #pragma unroll
        for (int kk = 0; kk < 2; ++kk) {
            f32x4 f0 = *(const f32x4*)(qrow + 32 * kk);
            f32x4 f1 = *(const f32x4*)(qrow + 32 * kk + 4);
            bf16x8 b;
            #pragma unroll
            for (int e = 0; e < 4; ++e) { b[e] = (__bf16)f0[e]; b[4 + e] = (__bf16)f1[e]; }
            bq[kk] = b;
        }
    }

    const uint2* mrow = (const uint2*)(Mbits + ((size_t)h * S_ + q_g) * 64);
    const char* gK = Ktiles + (size_t)h * 64 * 8192;
    const char* gV = Vtiles + (size_t)h * 64 * 8192;
    char* Pb = smem + 32768 + wave * 2048;

    float m2 = -INFINITY, lsum = 0.f;
    f32x4 acc[4] = {};

    auto stage = [&](int buf, int c) {
        const char* sk = gK + (size_t)c * 8192 + tid * 16;
        const char* sv = gV + (size_t)c * 8192 + tid * 16;
        char* dk = smem + buf * 16384 + tid * 16;
        gld16(sk,        dk);
        gld16(sk + 4096, dk + 4096);
        gld16(sv,        dk + 8192);
        gld16(sv + 4096, dk + 12288);
    };

    stage(0, 0);
    __syncthreads();                    // compiler drains vmcnt before barrier
    int cur = 0;

    for (int c = 0; c < NCH; ++c) {
        if (c + 1 < NCH) stage(cur ^ 1, c + 1);   // prefetch overlaps compute
        const uint2 mb = mrow[c];                  // dropout bits for this chunk

        const char* Kb = smem + cur * 16384;
        const char* Vb = Kb + 8192;
        const int kvb = c * 64;

        // ---- QK^T (swapped): lane holds s for q=q_g, kv = kvb + 16t + 4g + i
        float p[4][4];
        float cmax = -INFINITY;
        #pragma unroll
        for (int t = 0; t < 4; ++t) {
            f32x4 st = {0.f, 0.f, 0.f, 0.f};
            #pragma unroll
            for (int kk = 0; kk < 2; ++kk) {
                bf16x8 ak = *(const bf16x8*)(Kb + (16 * t + lq) * 128 + ((16 * g + 64 * kk) ^ swz));
                st = __builtin_amdgcn_mfma_f32_16x16x32_bf16(ak, bq[kk], st, 0, 0, 0);
            }
            #pragma unroll
            for (int i = 0; i < 4; ++i) {
                const int kvg = kvb + t * 16 + g * 4 + i;
                const bool one = (kvg < S_) ? (kvg > q_g) : ((kvg - S_) <= q_g);
                // log2 domain: (s*0.125 + mask) * log2(e)
                float v = st[i] * (0.125f * LOG2E) + (one ? LOG2E : 0.f);
                p[t][i] = v;
                cmax = fmaxf(cmax, v);
            }
        }
        cmax = fmaxf(cmax, __shfl_xor(cmax, 16));
        cmax = fmaxf(cmax, __shfl_xor(cmax, 32));

        const float mnew = fmaxf(m2, cmax);
        const float corr = exp2f(m2 - mnew);      // first chunk: exp2(-inf)=0
        float psum = 0.f;
        #pragma unroll
        for (int t = 0; t < 4; ++t)
            #pragma unroll
            for (int i = 0; i < 4; ++i) { p[t][i] = exp2f(p[t][i] - mnew); psum += p[t][i]; }
        psum += __shfl_xor(psum, 16);
        psum += __shfl_xor(psum, 32);
        lsum = lsum * corr + psum;                // denominator WITHOUT dropout
        m2 = mnew;

        // ---- dropout (bit-packed) + pack P to per-wave swizzled LDS tile
        #pragma unroll
        for (int t = 0; t < 4; ++t) {
            const unsigned w = (t < 2) ? mb.x : mb.y;
            const int sh = (t & 1) * 16 + g * 4;
            bf16x4 pb;
            #pragma unroll
            for (int i = 0; i < 4; ++i)
                pb[i] = (__bf16)(((w >> (sh + i)) & 1u) ? p[t][i] : 0.f);
            *(bf16x4*)(Pb + lq * 128 + ((32 * t + 8 * g) ^ swz)) = pb;
        }

        // ---- rescale accumulator (acc row q = g*4+i; state lives in lane g*4+i)
        #pragma unroll
        for (int i = 0; i < 4; ++i) {
            const float cr = __shfl(corr, g * 4 + i);
            #pragma unroll
            for (int nt = 0; nt < 4; ++nt) acc[nt][i] *= cr;
        }

        asm volatile("s_waitcnt lgkmcnt(0)" ::: "memory");
        __builtin_amdgcn_sched_barrier(0);

        // ---- PV: out += P[16q x 64kv] @ V[64kv x 64d]
        #pragma unroll
        for (int c2 = 0; c2 < 2; ++c2) {
            bf16x8 ap = *(const bf16x8*)(Pb + lq * 128 + ((64 * c2 + 16 * g) ^ swz));
            #pragma unroll
            for (int nt = 0; nt < 4; ++nt) {
                bf16x8 bv = *(const bf16x8*)(Vb + (16 * nt + lq) * 128 + ((64 * c2 + 16 * g) ^ swz));
                acc[nt] = __builtin_amdgcn_mfma_f32_16x16x32_bf16(ap, bv, acc[nt], 0, 0, 0);
            }
        }

        __syncthreads();   // drains next-chunk stage (vmcnt 0) + guards buffers
        cur ^= 1;
    }

    // ---- epilogue: out = acc * KEEP_SCALE / l
    float inv[4];
    #pragma unroll
    for (int i = 0; i < 4; ++i) inv[i] = KEEP_SCALE / __shfl(lsum, g * 4 + i);
    float* orow = Out + ((size_t)h * S_ + q0 + g * 4) * D_;
    #pragma unroll
    for (int i = 0; i < 4; ++i)
        #pragma unroll
        for (int nt = 0; nt < 4; ++nt)
            orow[i * D_ + nt * 16 + lq] = acc[nt][i] * inv[i];
}

extern "C" void kernel_launch(void* const* d_in, const int* in_sizes, int n_in,
                              void* d_out, int out_size, void* d_ws, size_t ws_size,
                              hipStream_t stream) {
    const float* Q = (const float*)d_in[0];
    const float* K = (const float*)d_in[1];
    const float* V = (const float*)d_in[2];
    const unsigned char* M = (const unsigned char*)d_in[3];
    char* ws = (char*)d_ws;
    int* flag = (int*)(ws + WS_FLAG);
    unsigned long long* mbits = (unsigned long long*)(ws + WS_MBITS);
    char* kt = ws + WS_K;
    char* vt = ws + WS_V;

    detect_mask<<<1, 256, 0, stream>>>((const unsigned*)M, flag);
    pack_mask<<<2048, 256, 0, stream>>>(M, (const unsigned*)M, flag, mbits);
    conv_k<<<2048, 256, 0, stream>>>(K, kt);
    conv_v<<<2048, 256, 0, stream>>>(V, vt);
    attn_fwd<<<512, 256, 0, stream>>>(Q, mbits, kt, vt, (float*)d_out);
}

// Round 3
// 308.203 us; speedup vs baseline: 1.0892x; 1.0892x over previous
//
#include <hip/hip_runtime.h>
#include <hip/hip_bf16.h>

// B=1, H=16, S=2048, KV=4096, D=64
// out[q][d] = (KEEP/sum_k p_k) * sum_k (drop_k * p_k * V[k][d])
// STATIC-MAX softmax: p = exp(s - 8); s = qk/8 + {0,1} mask, |s| <~ 7 so no
// overflow/underflow; partials across KV splits are directly additive.

#define H_   16
#define S_   2048
#define KV_  4096
#define D_   64
#define NCH  64                 // KV_/64 chunks total
#define NSPLIT 2                // KV split factor
#define LOG2E 1.4426950408889634f

using bf16x8 = __attribute__((ext_vector_type(8))) __bf16;
using bf16x4 = __attribute__((ext_vector_type(4))) __bf16;
using f32x4  = __attribute__((ext_vector_type(4))) float;

constexpr float KEEP_SCALE = (float)(1.0 / (1.0 - 0.31881923790897965));

// ---- workspace layout (~65MB of the ~2GB ws) ----
#define WS_FLAG   0
#define WS_MBITS  256                        // 16 MB  (32768 rows * 64 u64)
#define WS_K      (WS_MBITS + 16777216)      //  8 MB  bf16 swizzled K tiles
#define WS_V      (WS_K + 8388608)           //  8 MB  bf16 swizzled V^T tiles
#define WS_PART   (WS_V + 8388608)           // 16 MB  f32 partial acc [2][H*S][64]
#define WS_LS     (WS_PART + 33554432)       // 256 KB f32 partial lsum [2][H*S]

// ---------------------------------------------------------------------------
__global__ void detect_mask(const unsigned* __restrict__ m, int* __restrict__ flag) {
    __shared__ int bad;
    if (threadIdx.x == 0) bad = 0;
    __syncthreads();
    int ok = 1;
    for (int i = threadIdx.x; i < 4096; i += blockDim.x) {
        unsigned w = m[i];
        if (w > 1u && w != 0x3F800000u) ok = 0;
    }
    if (!ok) atomicOr(&bad, 1);
    __syncthreads();
    if (threadIdx.x == 0) *flag = bad;
}

// Bit-pack drop_mask: u64 word W = bits for elements [W*64, W*64+64).
__global__ __launch_bounds__(256)
void pack_mask(const unsigned char* __restrict__ mb, const unsigned* __restrict__ mw,
               const int* __restrict__ flag, unsigned long long* __restrict__ bits) {
    const int lane = threadIdx.x & 63;
    const int wid  = (blockIdx.x * blockDim.x + threadIdx.x) >> 6;
    const int nw   = (gridDim.x * blockDim.x) >> 6;
    const bool byteMode = (*flag != 0);
    const int NW = (H_ * S_) * (KV_ / 64);
    for (int W = wid; W < NW; W += nw) {
        const size_t base = (size_t)W * 64 + lane;
        bool keep = byteMode ? (mb[base] != 0) : (mw[base] != 0);
        unsigned long long b = __ballot(keep);
        if (lane == 0) bits[W] = b;
    }
}

// K -> bf16 tiles [h][chunk][8192B], pre-swizzled for linear global_load_lds:
// LDS byte o holds K[row=o>>7][colbyte = (o&127) ^ ((row&7)<<4)].
__global__ __launch_bounds__(256)
void conv_k(const float* __restrict__ K, char* __restrict__ out) {
    const unsigned u = blockIdx.x * 256 + threadIdx.x;   // 16B unit (524288)
    const unsigned tile = u >> 9;
    const unsigned w = u & 511;
    const unsigned row = w >> 3;
    const unsigned colb = ((w & 7) * 16) ^ ((row & 7) << 4);
    const unsigned dcol = colb >> 1;
    const unsigned h = tile >> 6, c = tile & 63;
    const float* src = K + (((size_t)h * KV_) + c * 64 + row) * D_ + dcol;
    f32x4 f0 = *(const f32x4*)src;
    f32x4 f1 = *(const f32x4*)(src + 4);
    bf16x8 b;
    #pragma unroll
    for (int e = 0; e < 4; ++e) { b[e] = (__bf16)f0[e]; b[4 + e] = (__bf16)f1[e]; }
    *(bf16x8*)(out + (size_t)u * 16) = b;
}

// V^T tiles: row = d, cols = 64 kv of chunk, same swizzle.
__global__ __launch_bounds__(256)
void conv_v(const float* __restrict__ V, char* __restrict__ out) {
    const unsigned u = blockIdx.x * 256 + threadIdx.x;
    const unsigned tile = u >> 9;
    const unsigned w = u & 511;
    const unsigned d = w >> 3;
    const unsigned colb = ((w & 7) * 16) ^ ((d & 7) << 4);
    const unsigned kv0 = colb >> 1;
    const unsigned h = tile >> 6, c = tile & 63;
    const float* src = V + (((size_t)h * KV_) + c * 64 + kv0) * D_ + d;
    bf16x8 b;
    #pragma unroll
    for (int j = 0; j < 8; ++j) b[j] = (__bf16)src[j * D_];
    *(bf16x8*)(out + (size_t)u * 16) = b;
}

// ---------------------------------------------------------------------------
__device__ __forceinline__ void gld16(const void* g, void* l) {
    __builtin_amdgcn_global_load_lds(
        (const __attribute__((address_space(1))) unsigned*)g,
        (__attribute__((address_space(3))) unsigned*)l, 16, 0, 0);
}

// 4 waves/block, 16 q/wave, chunk=64 kv, KV split across NSPLIT blocks.
__global__ __launch_bounds__(256, 4)
void attn_fwd(const float* __restrict__ Q,
              const unsigned long long* __restrict__ Mbits,
              const char* __restrict__ Ktiles,
              const char* __restrict__ Vtiles,
              float* __restrict__ Part,
              float* __restrict__ Ls)
{
    __shared__ char smem[2 * 16384 + 4 * 2048];   // 2 dbuf (K|V) + 4 P tiles

    const int tid  = threadIdx.x;
    const int wave = tid >> 6;
    const int lane = tid & 63;
    const int lq   = lane & 15;
    const int g    = lane >> 4;
    const int swz  = (lq & 7) << 4;

    // XCD-aware bijective swizzle (1024 % 8 == 0)
    const int bid = blockIdx.x;
    const int wg  = (bid & 7) * 128 + (bid >> 3);
    const int h     = wg >> 6;          // 0..15
    const int qb    = (wg >> 1) & 31;   // 0..31
    const int split = wg & 1;           // 0..1
    const int q0  = qb * 64 + wave * 16;
    const int q_g = q0 + lq;

    // Q fragments (B operand): lane holds Q[q_g][g*8 + 32*kk + e]
    bf16x8 bq[2];
    {
        const float* qrow = Q + ((size_t)h * S_ + q_g) * D_ + g * 8;
        #pragma unroll
        for (int kk = 0; kk < 2; ++kk) {
            f32x4 f0 = *(const f32x4*)(qrow + 32 * kk);
            f32x4 f1 = *(const f32x4*)(qrow + 32 * kk + 4);
            bf16x8 b;
            #pragma unroll
            for (int e = 0; e < 4; ++e) { b[e] = (__bf16)f0[e]; b[4 + e] = (__bf16)f1[e]; }
            bq[kk] = b;
        }
    }

    const uint2* mrow = (const uint2*)(Mbits + ((size_t)h * S_ + q_g) * 64);
    const char* gK = Ktiles + (size_t)h * 64 * 8192;
    const char* gV = Vtiles + (size_t)h * 64 * 8192;
    char* Pb = smem + 32768 + wave * 2048;

    float lsum = 0.f;          // per-lane partial denominator (no dropout)
    f32x4 acc[4] = {};

    auto stage = [&](int buf, int c) {
        const char* sk = gK + (size_t)c * 8192 + tid * 16;
        const char* sv = gV + (size_t)c * 8192 + tid * 16;
        char* dk = smem + buf * 16384 + tid * 16;
        gld16(sk,        dk);
        gld16(sk + 4096, dk + 4096);
        gld16(sv,        dk + 8192);
        gld16(sv + 4096, dk + 12288);
    };

    const int cStart = split * (NCH / NSPLIT);
    const int cEnd   = cStart + (NCH / NSPLIT);

    stage(0, cStart);
    __syncthreads();
    int cur = 0;

    for (int c = cStart; c < cEnd; ++c) {
        if (c + 1 < cEnd) stage(cur ^ 1, c + 1);
        const uint2 mb = mrow[c];

        const char* Kb = smem + cur * 16384;
        const char* Vb = Kb + 8192;
        const int kvb = c * 64;

        // ---- QK^T (swapped): lane holds s for q=q_g, kv = kvb + 16t + 4g + i
        float p[4][4];
        #pragma unroll
        for (int t = 0; t < 4; ++t) {
            f32x4 st = {0.f, 0.f, 0.f, 0.f};
            #pragma unroll
            for (int kk = 0; kk < 2; ++kk) {
                bf16x8 ak = *(const bf16x8*)(Kb + (16 * t + lq) * 128 + ((16 * g + 64 * kk) ^ swz));
                st = __builtin_amdgcn_mfma_f32_16x16x32_bf16(ak, bq[kk], st, 0, 0, 0);
            }
            #pragma unroll
            for (int i = 0; i < 4; ++i) {
                const int kvg = kvb + t * 16 + g * 4 + i;
                const bool one = (kvg < S_) ? (kvg > q_g) : ((kvg - S_) <= q_g);
                // p = exp(s - 8) computed as exp2(fma(..)): NO cross-lane ops.
                float v = fmaf(st[i], 0.18033688011112043f,
                               one ? -10.098865286222744f : -11.541560327111707f);
                float pp = exp2f(v);
                p[t][i] = pp;
                lsum += pp;
            }
        }

        // ---- dropout (bit-packed) + pack P (bf16) into swizzled LDS tile
        #pragma unroll
        for (int t = 0; t < 4; ++t) {
            const unsigned w = (t < 2) ? mb.x : mb.y;
            const int sh = (t & 1) * 16 + g * 4;
            bf16x4 pb;
            #pragma unroll
            for (int i = 0; i < 4; ++i)
                pb[i] = (__bf16)(((w >> (sh + i)) & 1u) ? p[t][i] : 0.f);
            *(bf16x4*)(Pb + lq * 128 + ((32 * t + 8 * g) ^ swz)) = pb;
        }

        asm volatile("s_waitcnt lgkmcnt(0)" ::: "memory");
        __builtin_amdgcn_sched_barrier(0);

        // ---- PV: acc += P[16q x 64kv] @ V[64kv x 64d]
        #pragma unroll
        for (int c2 = 0; c2 < 2; ++c2) {
            bf16x8 ap = *(const bf16x8*)(Pb + lq * 128 + ((64 * c2 + 16 * g) ^ swz));
            #pragma unroll
            for (int nt = 0; nt < 4; ++nt) {
                bf16x8 bv = *(const bf16x8*)(Vb + (16 * nt + lq) * 128 + ((64 * c2 + 16 * g) ^ swz));
                acc[nt] = __builtin_amdgcn_mfma_f32_16x16x32_bf16(ap, bv, acc[nt], 0, 0, 0);
            }
        }

        __syncthreads();
        cur ^= 1;
    }

    // ---- epilogue: one-time cross-group reduce of lsum; write partials
    lsum += __shfl_xor(lsum, 16);
    lsum += __shfl_xor(lsum, 32);
    if (g == 0) Ls[(size_t)(split * H_ + h) * S_ + q_g] = lsum;

    float* pa = Part + (((size_t)(split * H_ + h) * S_) + q0 + g * 4) * D_;
    #pragma unroll
    for (int i = 0; i < 4; ++i)
        #pragma unroll
        for (int nt = 0; nt < 4; ++nt)
            pa[i * D_ + nt * 16 + lq] = acc[nt][i];
}

// out = KEEP * (part0 + part1) / (l0 + l1)
__global__ __launch_bounds__(256)
void combine(const float* __restrict__ Part, const float* __restrict__ Ls,
             float* __restrict__ Out) {
    const int idx = blockIdx.x * 256 + threadIdx.x;   // H*S*16 = 524288
    const int r  = idx >> 4;                          // row h*S+q
    const int dg = (idx & 15) * 4;
    const f32x4 a = *(const f32x4*)(Part + (size_t)r * D_ + dg);
    const f32x4 b = *(const f32x4*)(Part + (size_t)(H_ * S_ + r) * D_ + dg);
    const float l = Ls[r] + Ls[H_ * S_ + r];
    const float s = KEEP_SCALE / l;
    f32x4 o;
    #pragma unroll
    for (int e = 0; e < 4; ++e) o[e] = (a[e] + b[e]) * s;
    *(f32x4*)(Out + (size_t)r * D_ + dg) = o;
}

extern "C" void kernel_launch(void* const* d_in, const int* in_sizes, int n_in,
                              void* d_out, int out_size, void* d_ws, size_t ws_size,
                              hipStream_t stream) {
    const float* Q = (const float*)d_in[0];
    const float* K = (const float*)d_in[1];
    const float* V = (const float*)d_in[2];
    const unsigned char* M = (const unsigned char*)d_in[3];
    char* ws = (char*)d_ws;
    int* flag = (int*)(ws + WS_FLAG);
    unsigned long long* mbits = (unsigned long long*)(ws + WS_MBITS);
    char* kt = ws + WS_K;
    char* vt = ws + WS_V;
    float* part = (float*)(ws + WS_PART);
    float* ls = (float*)(ws + WS_LS);

    detect_mask<<<1, 256, 0, stream>>>((const unsigned*)M, flag);
    pack_mask<<<2048, 256, 0, stream>>>(M, (const unsigned*)M, flag, mbits);
    conv_k<<<2048, 256, 0, stream>>>(K, kt);
    conv_v<<<2048, 256, 0, stream>>>(V, vt);
    attn_fwd<<<1024, 256, 0, stream>>>(Q, mbits, kt, vt, part, ls);
    combine<<<2048, 256, 0, stream>>>(part, ls, (float*)d_out);
}

// Round 4
// 235.464 us; speedup vs baseline: 1.4257x; 1.3089x over previous
//
#include <hip/hip_runtime.h>
#include <hip/hip_bf16.h>

// B=1, H=16, S=2048, KV=4096, D=64
// out[q][d] = (KEEP/sum_k p_k) * sum_k (drop_k * p_k * V[k][d])
// STATIC-MAX softmax: p = exp(s - 8); s = qk/8 + {0,1}; |s| <~ 7 -> safe,
// and partials across KV splits are directly additive (no running max).

#define H_   16
#define S_   2048
#define KV_  4096
#define D_   64
#define NCH  64                 // KV_/64 chunks total
#define NSPLIT 2

using bf16x8 = __attribute__((ext_vector_type(8))) __bf16;
using bf16x4 = __attribute__((ext_vector_type(4))) __bf16;
using f32x4  = __attribute__((ext_vector_type(4))) float;
using uintx4 = __attribute__((ext_vector_type(4))) unsigned;

constexpr float KEEP_SCALE = (float)(1.0 / (1.0 - 0.31881923790897965));

// ---- workspace layout (~65MB of ~2GB ws) ----
#define WS_FLAG   0
#define WS_MBITS  256                        // 16 MB packed mask bits
#define WS_K      (WS_MBITS + 16777216)      //  8 MB bf16 swizzled K tiles
#define WS_V      (WS_K + 8388608)           //  8 MB bf16 swizzled V^T tiles
#define WS_PART   (WS_V + 8388608)           // 16 MB f32 partial acc
#define WS_LS     (WS_PART + 33554432)       // 256 KB f32 partial lsum

// ---------------------------------------------------------------------------
__global__ void detect_mask(const unsigned* __restrict__ m, int* __restrict__ flag) {
    __shared__ int bad;
    if (threadIdx.x == 0) bad = 0;
    __syncthreads();
    int ok = 1;
    for (int i = threadIdx.x; i < 4096; i += blockDim.x) {
        unsigned w = m[i];
        if (w > 1u && w != 0x3F800000u) ok = 0;
    }
    if (!ok) atomicOr(&bad, 1);
    __syncthreads();
    if (threadIdx.x == 0) *flag = bad;
}

// ---------------------------------------------------------------------------
// Pack drop_mask to bits, coalesced. Output byte b covers elements 8b..8b+7
// (bit k = element 8b+k nonzero) -> u64 word W bit j = element 64W+j.
// ---------------------------------------------------------------------------
__global__ __launch_bounds__(256)
void pack_mask(const unsigned long long* __restrict__ m8,
               const uintx4* __restrict__ mw,
               const int* __restrict__ flag, unsigned char* __restrict__ bits) {
    const bool byteMode = (*flag != 0);
    const int NT = (H_ * S_ * KV_) / 8;       // 16.78M output bytes
    const int stride = gridDim.x * 256;
    if (byteMode) {
        for (int i = blockIdx.x * 256 + threadIdx.x; i < NT; i += stride) {
            unsigned long long x = m8[i];
            // per-byte nonzero -> bit7, then collapse bytes to bits via mul
            unsigned long long t = ((x & 0x7F7F7F7F7F7F7F7FULL) + 0x7F7F7F7F7F7F7F7FULL) | x;
            unsigned long long nz = (t >> 7) & 0x0101010101010101ULL;
            bits[i] = (unsigned char)((nz * 0x0102040810204080ULL) >> 56);
        }
    } else {
        for (int i = blockIdx.x * 256 + threadIdx.x; i < NT; i += stride) {
            uintx4 a = mw[2 * i], b = mw[2 * i + 1];
            unsigned v = 0;
            #pragma unroll
            for (int e = 0; e < 4; ++e) v |= (a[e] != 0u ? 1u : 0u) << e;
            #pragma unroll
            for (int e = 0; e < 4; ++e) v |= (b[e] != 0u ? 1u : 0u) << (4 + e);
            bits[i] = (unsigned char)v;
        }
    }
}

// ---------------------------------------------------------------------------
// K -> bf16 tiles [h][chunk][8192B], pre-swizzled for linear global_load_lds:
// LDS byte o holds K[row=o>>7][colbyte = (o&127) ^ ((row&7)<<4)].
// ---------------------------------------------------------------------------
__global__ __launch_bounds__(256)
void conv_k(const float* __restrict__ K, char* __restrict__ out) {
    const unsigned u = blockIdx.x * 256 + threadIdx.x;   // 16B unit (524288)
    const unsigned tile = u >> 9;
    const unsigned w = u & 511;
    const unsigned row = w >> 3;
    const unsigned colb = ((w & 7) * 16) ^ ((row & 7) << 4);
    const unsigned dcol = colb >> 1;
    const unsigned h = tile >> 6, c = tile & 63;
    const float* src = K + (((size_t)h * KV_) + c * 64 + row) * D_ + dcol;
    f32x4 f0 = *(const f32x4*)src;
    f32x4 f1 = *(const f32x4*)(src + 4);
    bf16x8 b;
    #pragma unroll
    for (int e = 0; e < 4; ++e) { b[e] = (__bf16)f0[e]; b[4 + e] = (__bf16)f1[e]; }
    *(bf16x8*)(out + (size_t)u * 16) = b;
}

// V^T tiles via per-block LDS transpose: coalesced in, coalesced out.
__global__ __launch_bounds__(256)
void conv_v(const float* __restrict__ V, char* __restrict__ out) {
    __shared__ __bf16 T[64][72];                 // [d][kv], 144B row stride
    const int tile = blockIdx.x;                 // h*64 + c
    const int h = tile >> 6, c = tile & 63;
    const float* src = V + ((size_t)h * KV_ + c * 64) * D_;
    const int tid = threadIdx.x;
    #pragma unroll
    for (int r = 0; r < 4; ++r) {
        const int off = r * 1024 + tid * 4;      // flat float index
        const int kv = off >> 6, d = off & 63;
        f32x4 f = *(const f32x4*)(src + off);
        #pragma unroll
        for (int e = 0; e < 4; ++e) T[d + e][kv] = (__bf16)f[e];
    }
    __syncthreads();
    char* dst = out + (size_t)tile * 8192;
    #pragma unroll
    for (int r = 0; r < 2; ++r) {
        const int u = r * 256 + tid;             // 16B unit (512/tile)
        const int d = u >> 3;
        const int colb = ((u & 7) * 16) ^ ((d & 7) << 4);
        const int kv0 = colb >> 1;
        *(bf16x8*)(dst + (size_t)u * 16) = *(const bf16x8*)&T[d][kv0];
    }
}

// ---------------------------------------------------------------------------
__device__ __forceinline__ void gld16(const void* g, void* l) {
    __builtin_amdgcn_global_load_lds(
        (const __attribute__((address_space(1))) unsigned*)g,
        (__attribute__((address_space(3))) unsigned*)l, 16, 0, 0);
}

// 4 waves/block, 16 q/wave, chunk=64 kv, KV split across NSPLIT blocks.
__global__ __launch_bounds__(256, 4)
void attn_fwd(const float* __restrict__ Q,
              const unsigned long long* __restrict__ Mbits,
              const char* __restrict__ Ktiles,
              const char* __restrict__ Vtiles,
              float* __restrict__ Part,
              float* __restrict__ Ls)
{
    __shared__ char smem[2 * 16384 + 4 * 2048];   // 2 dbuf (K|V) + 4 P tiles

    const int tid  = threadIdx.x;
    const int wave = tid >> 6;
    const int lane = tid & 63;
    const int lq   = lane & 15;
    const int g    = lane >> 4;
    const int swz  = (lq & 7) << 4;

    // XCD-aware bijective swizzle (1024 % 8 == 0)
    const int bid = blockIdx.x;
    const int wg  = (bid & 7) * 128 + (bid >> 3);
    const int h     = wg >> 6;
    const int qb    = (wg >> 1) & 31;
    const int split = wg & 1;
    const int q0  = qb * 64 + wave * 16;
    const int q_g = q0 + lq;

    // Q fragments (B operand): lane holds Q[q_g][g*8 + 32*kk + e]
    bf16x8 bq[2];
    {
        const float* qrow = Q + ((size_t)h * S_ + q_g) * D_ + g * 8;
        #pragma unroll
        for (int kk = 0; kk < 2; ++kk) {
            f32x4 f0 = *(const f32x4*)(qrow + 32 * kk);
            f32x4 f1 = *(const f32x4*)(qrow + 32 * kk + 4);
            bf16x8 b;
            #pragma unroll
            for (int e = 0; e < 4; ++e) { b[e] = (__bf16)f0[e]; b[4 + e] = (__bf16)f1[e]; }
            bq[kk] = b;
        }
    }

    const uint2* mrow = (const uint2*)(Mbits + ((size_t)h * S_ + q_g) * 64);
    const char* gK = Ktiles + (size_t)h * 64 * 8192;
    const char* gV = Vtiles + (size_t)h * 64 * 8192;
    char* Pb = smem + 32768 + wave * 2048;

    float lsum = 0.f;
    f32x4 acc[4] = {};

    auto stage = [&](int buf, int c) {
        const char* sk = gK + (size_t)c * 8192 + tid * 16;
        const char* sv = gV + (size_t)c * 8192 + tid * 16;
        char* dk = smem + buf * 16384 + tid * 16;
        gld16(sk,        dk);
        gld16(sk + 4096, dk + 4096);
        gld16(sv,        dk + 8192);
        gld16(sv + 4096, dk + 12288);
    };

    const int cStart = split * (NCH / NSPLIT);
    const int cEnd   = cStart + (NCH / NSPLIT);

    stage(0, cStart);
    uint2 mb = mrow[cStart];          // mask register double-buffer
    __syncthreads();
    int cur = 0;

    for (int c = cStart; c < cEnd; ++c) {
        if (c + 1 < cEnd) stage(cur ^ 1, c + 1);
        const uint2 mb_next = mrow[(c + 1 < cEnd) ? c + 1 : c];  // used NEXT iter

        const char* Kb = smem + cur * 16384;
        const char* Vb = Kb + 8192;
        const int kvb = c * 64;

        // ---- QK^T (swapped): lane holds s for q=q_g, kv = kvb + 16t + 4g + i
        float p[4][4];
        __builtin_amdgcn_s_setprio(1);
        f32x4 st[4];
        #pragma unroll
        for (int t = 0; t < 4; ++t) {
            st[t] = (f32x4){0.f, 0.f, 0.f, 0.f};
            #pragma unroll
            for (int kk = 0; kk < 2; ++kk) {
                bf16x8 ak = *(const bf16x8*)(Kb + (16 * t + lq) * 128 + ((16 * g + 64 * kk) ^ swz));
                st[t] = __builtin_amdgcn_mfma_f32_16x16x32_bf16(ak, bq[kk], st[t], 0, 0, 0);
            }
        }
        __builtin_amdgcn_s_setprio(0);

        float csum = 0.f;
        #pragma unroll
        for (int t = 0; t < 4; ++t) {
            float ts = 0.f;
            #pragma unroll
            for (int i = 0; i < 4; ++i) {
                const int kvg = kvb + t * 16 + g * 4 + i;
                const bool one = (kvg < S_) ? (kvg > q_g) : ((kvg - S_) <= q_g);
                // p = exp(s-8) as exp2(fma(..)); no cross-lane ops
                float v = fmaf(st[t][i], 0.18033688011112043f,
                               one ? -10.098865286222744f : -11.541560327111707f);
                float pp = exp2f(v);
                p[t][i] = pp;
                ts += pp;
            }
            csum += ts;
        }
        lsum += csum;

        // ---- dropout (bit-packed) + pack P (bf16) into swizzled LDS tile
        #pragma unroll
        for (int t = 0; t < 4; ++t) {
            const unsigned w = (t < 2) ? mb.x : mb.y;
            const int sh = (t & 1) * 16 + g * 4;
            bf16x4 pb;
            #pragma unroll
            for (int i = 0; i < 4; ++i)
                pb[i] = (__bf16)(((w >> (sh + i)) & 1u) ? p[t][i] : 0.f);
            *(bf16x4*)(Pb + lq * 128 + ((32 * t + 8 * g) ^ swz)) = pb;
        }

        asm volatile("s_waitcnt lgkmcnt(0)" ::: "memory");
        __builtin_amdgcn_sched_barrier(0);

        // ---- PV: acc += P[16q x 64kv] @ V[64kv x 64d]
        __builtin_amdgcn_s_setprio(1);
        #pragma unroll
        for (int c2 = 0; c2 < 2; ++c2) {
            bf16x8 ap = *(const bf16x8*)(Pb + lq * 128 + ((64 * c2 + 16 * g) ^ swz));
            #pragma unroll
            for (int nt = 0; nt < 4; ++nt) {
                bf16x8 bv = *(const bf16x8*)(Vb + (16 * nt + lq) * 128 + ((64 * c2 + 16 * g) ^ swz));
                acc[nt] = __builtin_amdgcn_mfma_f32_16x16x32_bf16(ap, bv, acc[nt], 0, 0, 0);
            }
        }
        __builtin_amdgcn_s_setprio(0);

        mb = mb_next;
        __syncthreads();
        cur ^= 1;
    }

    // ---- epilogue
    lsum += __shfl_xor(lsum, 16);
    lsum += __shfl_xor(lsum, 32);
    if (g == 0) Ls[(size_t)(split * H_ + h) * S_ + q_g] = lsum;

    float* pa = Part + (((size_t)(split * H_ + h) * S_) + q0 + g * 4) * D_;
    #pragma unroll
    for (int i = 0; i < 4; ++i)
        #pragma unroll
        for (int nt = 0; nt < 4; ++nt)
            pa[i * D_ + nt * 16 + lq] = acc[nt][i];
}

// out = KEEP * (part0 + part1) / (l0 + l1)
__global__ __launch_bounds__(256)
void combine(const float* __restrict__ Part, const float* __restrict__ Ls,
             float* __restrict__ Out) {
    const int idx = blockIdx.x * 256 + threadIdx.x;   // H*S*16
    const int r  = idx >> 4;
    const int dg = (idx & 15) * 4;
    const f32x4 a = *(const f32x4*)(Part + (size_t)r * D_ + dg);
    const f32x4 b = *(const f32x4*)(Part + (size_t)(H_ * S_ + r) * D_ + dg);
    const float l = Ls[r] + Ls[H_ * S_ + r];
    const float s = KEEP_SCALE / l;
    f32x4 o;
    #pragma unroll
    for (int e = 0; e < 4; ++e) o[e] = (a[e] + b[e]) * s;
    *(f32x4*)(Out + (size_t)r * D_ + dg) = o;
}

extern "C" void kernel_launch(void* const* d_in, const int* in_sizes, int n_in,
                              void* d_out, int out_size, void* d_ws, size_t ws_size,
                              hipStream_t stream) {
    const float* Q = (const float*)d_in[0];
    const float* K = (const float*)d_in[1];
    const float* V = (const float*)d_in[2];
    const unsigned char* M = (const unsigned char*)d_in[3];
    char* ws = (char*)d_ws;
    int* flag = (int*)(ws + WS_FLAG);
    unsigned long long* mbits = (unsigned long long*)(ws + WS_MBITS);
    char* kt = ws + WS_K;
    char* vt = ws + WS_V;
    float* part = (float*)(ws + WS_PART);
    float* ls = (float*)(ws + WS_LS);

    detect_mask<<<1, 256, 0, stream>>>((const unsigned*)M, flag);
    pack_mask<<<2048, 256, 0, stream>>>((const unsigned long long*)M, (const uintx4*)M,
                                        flag, (unsigned char*)mbits);
    conv_k<<<2048, 256, 0, stream>>>(K, kt);
    conv_v<<<1024, 256, 0, stream>>>(V, vt);
    attn_fwd<<<1024, 256, 0, stream>>>(Q, mbits, kt, vt, part, ls);
    combine<<<2048, 256, 0, stream>>>(part, ls, (float*)d_out);
}